// Round 15
// baseline (366.261 us; speedup 1.0000x reference)
//
#include <hip/hip_runtime.h>
#include <hip/hip_fp16.h>

#define BSZ 1024   // B
#define VSZ 4096   // V
#define NSB 128    // sinkhorn blocks (8 j-rows each)
#define RPB 8      // j-rows per sinkhorn block
#define KP  1040   // k_lds row stride (floats)
#define FBLK 512   // fused kernel grid
#define TSI 128    // cdist i-tile
#define TSJ 64     // cdist j-tile
#define LSTR 72    // u16 row stride (144 B): 2-way bank aliasing -> free (m136)

// ---------------- softmax(y/2) row-wise, writes u16 fixed-point probs --------
// Node 1. Also zeroes node-2's barrier flags (512x32 u32) and the 3x4096
// cpart rotation buffers — in-stream predecessor, so no memset node and no
// reliance on cross-replay workspace persistence (re-poison safe).
__global__ __launch_bounds__(256) void softmax_kernel(const float* __restrict__ ys,
                                                      const float* __restrict__ yt,
                                                      unsigned short* __restrict__ ps,
                                                      unsigned short* __restrict__ pt,
                                                      float* __restrict__ cpart,
                                                      unsigned* __restrict__ flags) {
    if (blockIdx.x < 64) flags[blockIdx.x * 256 + threadIdx.x] = 0u;        // 512*32 u32
    else if (blockIdx.x < 76) {
        float4 z4; z4.x = z4.y = z4.z = z4.w = 0.f;
        ((float4*)cpart)[(blockIdx.x - 64) * 256 + threadIdx.x] = z4;       // 3*4096 floats
    }
    int row = blockIdx.x;
    const float* src;
    unsigned short* dst;
    if (row < BSZ) { src = ys + (size_t)row * VSZ;         dst = ps + (size_t)row * VSZ; }
    else           { src = yt + (size_t)(row - BSZ) * VSZ; dst = pt + (size_t)(row - BSZ) * VSZ; }
    int t = threadIdx.x;
    float4 v[4];
    float m = -1e30f;
#pragma unroll
    for (int k = 0; k < 4; ++k) {
        v[k] = ((const float4*)src)[t + 256 * k];
        m = fmaxf(m, fmaxf(fmaxf(v[k].x, v[k].y), fmaxf(v[k].z, v[k].w)));
    }
#pragma unroll
    for (int d = 32; d >= 1; d >>= 1) m = fmaxf(m, __shfl_down(m, d));
    __shared__ float sred[4];
    __shared__ float sred2[4];
    int lane = t & 63, wid = t >> 6;
    if (lane == 0) sred[wid] = m;
    __syncthreads();
    m = fmaxf(fmaxf(sred[0], sred[1]), fmaxf(sred[2], sred[3]));
    const float C = 0.7213475204444817f;  // 0.5 * log2(e)  (T = 2)
    float s = 0.f;
#pragma unroll
    for (int k = 0; k < 4; ++k) {
        v[k].x = exp2f((v[k].x - m) * C);
        v[k].y = exp2f((v[k].y - m) * C);
        v[k].z = exp2f((v[k].z - m) * C);
        v[k].w = exp2f((v[k].w - m) * C);
        s += (v[k].x + v[k].y) + (v[k].z + v[k].w);
    }
#pragma unroll
    for (int d = 32; d >= 1; d >>= 1) s += __shfl_down(s, d);
    if (lane == 0) sred2[wid] = s;
    __syncthreads();
    s = (sred2[0] + sred2[1]) + (sred2[2] + sred2[3]);
    float inv = 65535.0f / s;  // fold quantization scale into the normalizer
#pragma unroll
    for (int k = 0; k < 4; ++k) {
        union { unsigned short h[4]; uint2 u; } o;
        o.h[0] = (unsigned short)__float2uint_rn(fminf(v[k].x * inv, 65535.0f));
        o.h[1] = (unsigned short)__float2uint_rn(fminf(v[k].y * inv, 65535.0f));
        o.h[2] = (unsigned short)__float2uint_rn(fminf(v[k].z * inv, 65535.0f));
        o.h[3] = (unsigned short)__float2uint_rn(fminf(v[k].w * inv, 65535.0f));
        ((uint2*)dst)[t + 256 * k] = o.u;
    }
}

// ------- grid barrier over nblk blocks (flag-based, co-resident blocks) ------
__device__ inline void grid_barrier_n(unsigned* flags, unsigned gen, int nblk) {
    __syncthreads();
    const int t = threadIdx.x;
    if (t == 0)  // RELEASE: flush this block's stores agent-wide
        __hip_atomic_store(&flags[blockIdx.x * 32], gen, __ATOMIC_RELEASE, __HIP_MEMORY_SCOPE_AGENT);
    for (int f = t; f < nblk; f += (int)blockDim.x) {
        while (__hip_atomic_load(&flags[f * 32], __ATOMIC_RELAXED, __HIP_MEMORY_SCOPE_AGENT) < gen)
            __builtin_amdgcn_s_sleep(1);
    }
    __syncthreads();
    if (t == 0)  // single ACQUIRE: one cache inv for the whole block
        (void)__hip_atomic_load(&flags[0], __ATOMIC_ACQUIRE, __HIP_MEMORY_SCOPE_AGENT);
    __syncthreads();
}

// ---------------- FUSED cdist + sinkhorn (node 2) ----------------------------
// R30. Phase B: R23 champion cdist VERBATIM (256 threads, 4 blocks/CU, LDS
// 27.6KB, transient staging — m114 overlap preserved; R27's 8-wave mistake
// avoided). One 512-block barrier (flags zeroed by node 1). Phase C: sinkhorn
// re-shaped to 128 blocks x 8 rows so K fits LDS (8x1040x4 = 33.3KB, UNION'd
// with the cdist buffers -> still 4 blocks/CU; R27's register-K went to
// scratch). Atomic fan-in kept at 32 via 4 cbuf copies (copy = blk>>5);
// b-row-reduce via wave shfl_xor + 4x8 LDS; final W recovered as log2(K)/CE
// in-register (no spart re-read). Kills one ~18us node.
__global__ __launch_bounds__(256, 4) void fused_cs_kernel(const unsigned short* __restrict__ psh,
                                                          const unsigned short* __restrict__ pth,
                                                          float* __restrict__ spart,
                                                          float* __restrict__ cpart,
                                                          float* __restrict__ outpart,
                                                          float* __restrict__ out,
                                                          unsigned* __restrict__ flags) {
    __shared__ __align__(16) unsigned char smem[RPB * KP * 4];  // 33,280 B union
    __shared__ float b_sh[RPB];
    __shared__ float redsm[4][RPB];
    const int t = threadIdx.x;
    const int blk = blockIdx.x;
    const int M = BSZ * BSZ;

    // ============ Phase B: cdist (R23 champion, verbatim logic) ============
    {
        unsigned short* sP = (unsigned short*)smem;                    // 18,432 B
        unsigned short* sQ = (unsigned short*)(smem + TSI * LSTR * 2); //  9,216 B
        const int bi = blk & 7;           // 8  i-panels
        const int bj = (blk >> 3) & 15;   // 16 j-panels
        const int bv = blk >> 7;          // 4  v-chunks
        const int cl = t & 15;   // i-lane (16)
        const int rl = t >> 4;   // j-lane (16)
        const int pr = t >> 1, pc = (t & 1) * 32;
        const int qr = t >> 2, qc = (t & 3) * 16;
        const unsigned short* gP = psh + (size_t)(bi * TSI + pr) * VSZ + bv * 1024 + pc;
        const unsigned short* gQ = pth + (size_t)(bj * TSJ + qr) * VSZ + bv * 1024 + qc;
        unsigned short* lP = &sP[pr * LSTR + pc];
        unsigned short* lQ = &sQ[qr * LSTR + qc];

        unsigned acc[4][8];
#pragma unroll
        for (int w = 0; w < 4; ++w)
#pragma unroll
            for (int u = 0; u < 8; ++u) acc[w][u] = 0u;

        for (int kt = 0; kt < 16; ++kt) {
            const unsigned short* gp = gP + kt * 64;
            const unsigned short* gq = gQ + kt * 64;
            uint4 a0 = *(const uint4*)(gp + 0);
            uint4 a1 = *(const uint4*)(gp + 8);
            uint4 a2 = *(const uint4*)(gp + 16);
            uint4 a3 = *(const uint4*)(gp + 24);
            uint4 b0 = *(const uint4*)(gq + 0);
            uint4 b1 = *(const uint4*)(gq + 8);
            __syncthreads();   // all waves finished reading previous tile
            *(uint4*)(lP + 0)  = a0;
            *(uint4*)(lP + 8)  = a1;
            *(uint4*)(lP + 16) = a2;
            *(uint4*)(lP + 24) = a3;
            *(uint4*)(lQ + 0)  = b0;
            *(uint4*)(lQ + 8)  = b1;
            __syncthreads();   // staging visible
            const unsigned short* pbase = sP + cl * LSTR;
            const unsigned short* qbase = sQ + rl * LSTR;
#pragma unroll
            for (int vv = 0; vv < 8; ++vv) {
                uint4 q[4];
#pragma unroll
                for (int w = 0; w < 4; ++w)
                    q[w] = *(const uint4*)(qbase + w * 16 * LSTR + vv * 8);
#pragma unroll
                for (int h = 0; h < 4; ++h) {
                    uint4 p0 = *(const uint4*)(pbase + (2 * h + 0) * 16 * LSTR + vv * 8);
                    uint4 p1 = *(const uint4*)(pbase + (2 * h + 1) * 16 * LSTR + vv * 8);
#pragma unroll
                    for (int w = 0; w < 4; ++w) {
                        unsigned a = acc[w][2 * h + 0];
                        a = __builtin_amdgcn_sad_u16(p0.x, q[w].x, a);
                        a = __builtin_amdgcn_sad_u16(p0.y, q[w].y, a);
                        a = __builtin_amdgcn_sad_u16(p0.z, q[w].z, a);
                        a = __builtin_amdgcn_sad_u16(p0.w, q[w].w, a);
                        acc[w][2 * h + 0] = a;
                        unsigned b = acc[w][2 * h + 1];
                        b = __builtin_amdgcn_sad_u16(p1.x, q[w].x, b);
                        b = __builtin_amdgcn_sad_u16(p1.y, q[w].y, b);
                        b = __builtin_amdgcn_sad_u16(p1.z, q[w].z, b);
                        b = __builtin_amdgcn_sad_u16(p1.w, q[w].w, b);
                        acc[w][2 * h + 1] = b;
                    }
                }
            }
        }

        float* outp = spart + (size_t)bv * M;
        const float SCL = 1.0f / 65535.0f;
#pragma unroll
        for (int w = 0; w < 4; ++w) {
            size_t jr = (size_t)(bj * TSJ + rl + 16 * w);
#pragma unroll
            for (int u = 0; u < 8; ++u) {
                int ic = bi * TSI + cl + 16 * u;
                outp[jr * BSZ + ic] = (float)acc[w][u] * SCL;
            }
        }
    }

    grid_barrier_n(flags, 1u, FBLK);   // spart complete, device-visible
    if (blk >= NSB) return;            // non-sinkhorn blocks exit (flags stay 1)

    // ============ Phase C: sinkhorn, 128 blocks x 8 rows ============
    float* k_lds = (float*)smem;       // [RPB][KP], overlays dead sP/sQ
    const int z = blk;
    const int j0 = z * RPB;
    const float CE = -14.426950408889634f;  // -log2(e)/eps, eps=0.1
#pragma unroll
    for (int q = 0; q < RPB; ++q) {
        size_t off = (size_t)(j0 + q) * BSZ + 4 * t;
        float4 w0 = *(const float4*)(spart + off);
        float4 w1 = *(const float4*)(spart + off + M);
        float4 w2 = *(const float4*)(spart + off + 2 * M);
        float4 w3 = *(const float4*)(spart + off + 3 * M);
        float4 k;
        k.x = exp2f(((w0.x + w1.x) + (w2.x + w3.x)) * CE);
        k.y = exp2f(((w0.y + w1.y) + (w2.y + w3.y)) * CE);
        k.z = exp2f(((w0.z + w1.z) + (w2.z + w3.z)) * CE);
        k.w = exp2f(((w0.w + w1.w) + (w2.w + w3.w)) * CE);
        *(float4*)(&k_lds[q * KP + 4 * t]) = k;
    }
    if (t < RPB) b_sh[t] = 1.0f;
    __syncthreads();
    const int colq = (t + 2 * z) & 255;   // staggered column-quad
    const int c0 = 4 * colq;
    const int g = z >> 5;                 // cbuf copy 0..3 (fan-in stays 32)
    unsigned gen = 2u;
    float4 a4 = {0.f, 0.f, 0.f, 0.f};
    for (int it = 0; it < 20; ++it) {
        float* cbuf = cpart + (size_t)(it % 3) * 4096;
        float4 s = {0.f, 0.f, 0.f, 0.f};
#pragma unroll
        for (int q = 0; q < RPB; ++q) {
            float4 k = *(const float4*)(&k_lds[q * KP + c0]);
            float bb = b_sh[q];
            s.x += k.x * bb; s.y += k.y * bb; s.z += k.z * bb; s.w += k.w * bb;
        }
        float* dc = cbuf + g * 1024 + c0;
        (void)__hip_atomic_fetch_add(dc + 0, s.x, __ATOMIC_RELAXED, __HIP_MEMORY_SCOPE_AGENT);
        (void)__hip_atomic_fetch_add(dc + 1, s.y, __ATOMIC_RELAXED, __HIP_MEMORY_SCOPE_AGENT);
        (void)__hip_atomic_fetch_add(dc + 2, s.z, __ATOMIC_RELAXED, __HIP_MEMORY_SCOPE_AGENT);
        (void)__hip_atomic_fetch_add(dc + 3, s.w, __ATOMIC_RELAXED, __HIP_MEMORY_SCOPE_AGENT);
        grid_barrier_n(flags, gen++, NSB);
        float4 c0v = *(const float4*)(cbuf + 0 * 1024 + c0);
        float4 c1v = *(const float4*)(cbuf + 1 * 1024 + c0);
        float4 c2v = *(const float4*)(cbuf + 2 * 1024 + c0);
        float4 c3v = *(const float4*)(cbuf + 3 * 1024 + c0);
        // re-zero own slice of the rotation buffer iter it+2 uses (128*32=4096)
        if (t < 32) cpart[(size_t)((it + 2) % 3) * 4096 + z * 32 + t] = 0.f;
        a4.x = 1.0f / ((c0v.x + c1v.x) + (c2v.x + c3v.x));
        a4.y = 1.0f / ((c0v.y + c1v.y) + (c2v.y + c3v.y));
        a4.z = 1.0f / ((c0v.z + c1v.z) + (c2v.z + c3v.z));
        a4.w = 1.0f / ((c0v.w + c1v.w) + (c2v.w + c3v.w));
        // b-pass: per-row dot with a, block-wide reduce
#pragma unroll
        for (int q = 0; q < RPB; ++q) {
            float4 k = *(const float4*)(&k_lds[q * KP + c0]);
            float pq = (k.x * a4.x + k.y * a4.y) + (k.z * a4.z + k.w * a4.w);
            pq += __shfl_xor(pq, 1);
            pq += __shfl_xor(pq, 2);
            pq += __shfl_xor(pq, 4);
            pq += __shfl_xor(pq, 8);
            pq += __shfl_xor(pq, 16);
            pq += __shfl_xor(pq, 32);
            if ((t & 63) == 0) redsm[t >> 6][q] = pq;
        }
        __syncthreads();
        if (t < RPB) {
            float sb = (redsm[0][t] + redsm[1][t]) + (redsm[2][t] + redsm[3][t]);
            b_sh[t] = 1.0f / sb;
        }
        __syncthreads();
    }
    // final: sum P*W; W recovered as log2(K)/CE (K >= 2^-29, no underflow)
    {
        const float ICE = 1.0f / CE;
        float fin = 0.f;
#pragma unroll
        for (int q = 0; q < RPB; ++q) {
            float4 k = *(const float4*)(&k_lds[q * KP + c0]);
            float4 w;
            w.x = log2f(k.x) * ICE;
            w.y = log2f(k.y) * ICE;
            w.z = log2f(k.z) * ICE;
            w.w = log2f(k.w) * ICE;
            fin += b_sh[q] * ((a4.x * k.x * w.x + a4.y * k.y * w.y) +
                              (a4.z * k.z * w.z + a4.w * k.w * w.w));
        }
        fin += __shfl_xor(fin, 1);
        fin += __shfl_xor(fin, 2);
        fin += __shfl_xor(fin, 4);
        fin += __shfl_xor(fin, 8);
        fin += __shfl_xor(fin, 16);
        fin += __shfl_xor(fin, 32);
        if ((t & 63) == 0) redsm[t >> 6][0] = fin;
        __syncthreads();
        if (t == 0)
            outpart[z] = (redsm[0][0] + redsm[1][0]) + (redsm[2][0] + redsm[3][0]);
    }
    grid_barrier_n(flags, gen++, NSB);
    if (z == 0 && t == 0) {
        float ss = 0.f;
        for (int q = 0; q < NSB; ++q) ss += outpart[q];
        out[0] = 0.001f * ss;
    }
}

extern "C" void kernel_launch(void* const* d_in, const int* in_sizes, int n_in,
                              void* d_out, int out_size, void* d_ws, size_t ws_size,
                              hipStream_t stream) {
    const float* ys = (const float*)d_in[0];
    const float* yt = (const float*)d_in[1];
    float* ws = (float*)d_ws;
    unsigned short* psh = (unsigned short*)ws;                        // 1024x4096 u16
    unsigned short* pth = (unsigned short*)(ws + 2ull * 1024 * 1024); // 1024x4096 u16
    float* spart   = ws + 4ull * 1024 * 1024;              // 4 x 1M floats
    float* cpart   = spart + 4ull * BSZ * BSZ;             // 3 x 4096 floats
    float* outpart = cpart + 3ull * 4096;                  // 128 floats
    unsigned* flags = (unsigned*)(outpart + 256);          // FBLK x 32 uints
    float* outp    = (float*)d_out;

    softmax_kernel<<<dim3(2 * BSZ), dim3(256), 0, stream>>>(ys, yt, psh, pth, cpart, flags);
    fused_cs_kernel<<<dim3(FBLK), dim3(256), 0, stream>>>(psh, pth, spart, cpart,
                                                          outpart, outp, flags);
}

// Round 16
// 258.496 us; speedup vs baseline: 1.4169x; 1.4169x over previous
//
#include <hip/hip_runtime.h>
#include <hip/hip_fp16.h>

#define BSZ 1024   // B
#define VSZ 4096   // V
#define NBLK 32    // sinkhorn blocks (32 j-rows each, 512 threads)
#define JPB 32     // j's per sinkhorn block
#define KPAD 1040  // LDS row stride for K (1024 + 16 floats)

// ---------------- softmax(y/2) row-wise, writes u16 fixed-point probs --------
// Also zero-inits sinkhorn's flags + 3 rotating c-buffers (absorbed combine).
__global__ __launch_bounds__(256) void softmax_kernel(const float* __restrict__ ys,
                                                      const float* __restrict__ yt,
                                                      unsigned short* __restrict__ ps,
                                                      unsigned short* __restrict__ pt,
                                                      float* __restrict__ cpart,
                                                      unsigned* __restrict__ flags) {
    if (blockIdx.x == 0 && threadIdx.x < NBLK) flags[threadIdx.x * 32] = 0u;
    if (blockIdx.x >= 32 && blockIdx.x < 35) {
        float4 z4; z4.x = z4.y = z4.z = z4.w = 0.f;
        ((float4*)cpart)[(blockIdx.x - 32) * 256 + threadIdx.x] = z4;  // 3 x 1024 floats
    }
    int row = blockIdx.x;
    const float* src;
    unsigned short* dst;
    if (row < BSZ) { src = ys + (size_t)row * VSZ;         dst = ps + (size_t)row * VSZ; }
    else           { src = yt + (size_t)(row - BSZ) * VSZ; dst = pt + (size_t)(row - BSZ) * VSZ; }
    int t = threadIdx.x;
    float4 v[4];
    float m = -1e30f;
#pragma unroll
    for (int k = 0; k < 4; ++k) {
        v[k] = ((const float4*)src)[t + 256 * k];
        m = fmaxf(m, fmaxf(fmaxf(v[k].x, v[k].y), fmaxf(v[k].z, v[k].w)));
    }
#pragma unroll
    for (int d = 32; d >= 1; d >>= 1) m = fmaxf(m, __shfl_down(m, d));
    __shared__ float sred[4];
    __shared__ float sred2[4];
    int lane = t & 63, wid = t >> 6;
    if (lane == 0) sred[wid] = m;
    __syncthreads();
    m = fmaxf(fmaxf(sred[0], sred[1]), fmaxf(sred[2], sred[3]));
    const float C = 0.7213475204444817f;  // 0.5 * log2(e)  (T = 2)
    float s = 0.f;
#pragma unroll
    for (int k = 0; k < 4; ++k) {
        v[k].x = exp2f((v[k].x - m) * C);
        v[k].y = exp2f((v[k].y - m) * C);
        v[k].z = exp2f((v[k].z - m) * C);
        v[k].w = exp2f((v[k].w - m) * C);
        s += (v[k].x + v[k].y) + (v[k].z + v[k].w);
    }
#pragma unroll
    for (int d = 32; d >= 1; d >>= 1) s += __shfl_down(s, d);
    if (lane == 0) sred2[wid] = s;
    __syncthreads();
    s = (sred2[0] + sred2[1]) + (sred2[2] + sred2[3]);
    float inv = 65535.0f / s;  // fold quantization scale into the normalizer
#pragma unroll
    for (int k = 0; k < 4; ++k) {
        union { unsigned short h[4]; uint2 u; } o;
        o.h[0] = (unsigned short)__float2uint_rn(fminf(v[k].x * inv, 65535.0f));
        o.h[1] = (unsigned short)__float2uint_rn(fminf(v[k].y * inv, 65535.0f));
        o.h[2] = (unsigned short)__float2uint_rn(fminf(v[k].z * inv, 65535.0f));
        o.h[3] = (unsigned short)__float2uint_rn(fminf(v[k].w * inv, 65535.0f));
        ((uint2*)dst)[t + 256 * k] = o.u;
    }
}

// ---------------- W-partial: WT[j][i] = sum_v |ps[i,v] - pt[j,v]| ------------
// R23 champion, UNTOUCHED. 128x64 tile, 256 threads, 8x4 acc, single LDS
// buffer 27.6KB -> 4 blocks/CU at launch_bounds(256,4), transient staging
// regs. Both fusion directions measured WORSE: cdist+sinkhorn +100us (R27
// register-spill / R30 barrier-shape), softmax+cdist +13us vs 18us node save
// minus re-introduced memset node (R14).
#define TSI 128  // i-tile
#define TSJ 64   // j-tile
#define LSTR 72  // u16 row stride (144 B): 2-way bank aliasing -> free (m136)

__global__ __launch_bounds__(256, 4) void cdist_kernel(const unsigned short* __restrict__ psh,
                                                       const unsigned short* __restrict__ pth,
                                                       float* __restrict__ spart) {
    __shared__ unsigned short sP[TSI * LSTR];   // 18,432 B
    __shared__ unsigned short sQ[TSJ * LSTR];   //  9,216 B  (27.6 KB total)
    const int bi = blockIdx.x;   // 8  i-panels
    const int bj = blockIdx.y;   // 16 j-panels
    const int bv = blockIdx.z;   // 4  v-chunks
    const int t = threadIdx.x;
    const int cl = t & 15;   // i-lane (16)
    const int rl = t >> 4;   // j-lane (16)

    const int pr = t >> 1, pc = (t & 1) * 32;
    const int qr = t >> 2, qc = (t & 3) * 16;
    const unsigned short* gP = psh + (size_t)(bi * TSI + pr) * VSZ + bv * 1024 + pc;
    const unsigned short* gQ = pth + (size_t)(bj * TSJ + qr) * VSZ + bv * 1024 + qc;
    unsigned short* lP = &sP[pr * LSTR + pc];
    unsigned short* lQ = &sQ[qr * LSTR + qc];

    unsigned acc[4][8];
#pragma unroll
    for (int w = 0; w < 4; ++w)
#pragma unroll
        for (int u = 0; u < 8; ++u) acc[w][u] = 0u;

    for (int kt = 0; kt < 16; ++kt) {
        const unsigned short* gp = gP + kt * 64;
        const unsigned short* gq = gQ + kt * 64;
        uint4 a0 = *(const uint4*)(gp + 0);
        uint4 a1 = *(const uint4*)(gp + 8);
        uint4 a2 = *(const uint4*)(gp + 16);
        uint4 a3 = *(const uint4*)(gp + 24);
        uint4 b0 = *(const uint4*)(gq + 0);
        uint4 b1 = *(const uint4*)(gq + 8);
        __syncthreads();   // all waves finished reading previous tile
        *(uint4*)(lP + 0)  = a0;
        *(uint4*)(lP + 8)  = a1;
        *(uint4*)(lP + 16) = a2;
        *(uint4*)(lP + 24) = a3;
        *(uint4*)(lQ + 0)  = b0;
        *(uint4*)(lQ + 8)  = b1;
        __syncthreads();   // staging visible
        const unsigned short* pbase = sP + cl * LSTR;
        const unsigned short* qbase = sQ + rl * LSTR;
#pragma unroll
        for (int vv = 0; vv < 8; ++vv) {
            uint4 q[4];
#pragma unroll
            for (int w = 0; w < 4; ++w)
                q[w] = *(const uint4*)(qbase + w * 16 * LSTR + vv * 8);
#pragma unroll
            for (int h = 0; h < 4; ++h) {
                uint4 p0 = *(const uint4*)(pbase + (2 * h + 0) * 16 * LSTR + vv * 8);
                uint4 p1 = *(const uint4*)(pbase + (2 * h + 1) * 16 * LSTR + vv * 8);
#pragma unroll
                for (int w = 0; w < 4; ++w) {
                    unsigned a = acc[w][2 * h + 0];
                    a = __builtin_amdgcn_sad_u16(p0.x, q[w].x, a);
                    a = __builtin_amdgcn_sad_u16(p0.y, q[w].y, a);
                    a = __builtin_amdgcn_sad_u16(p0.z, q[w].z, a);
                    a = __builtin_amdgcn_sad_u16(p0.w, q[w].w, a);
                    acc[w][2 * h + 0] = a;
                    unsigned b = acc[w][2 * h + 1];
                    b = __builtin_amdgcn_sad_u16(p1.x, q[w].x, b);
                    b = __builtin_amdgcn_sad_u16(p1.y, q[w].y, b);
                    b = __builtin_amdgcn_sad_u16(p1.z, q[w].z, b);
                    b = __builtin_amdgcn_sad_u16(p1.w, q[w].w, b);
                    acc[w][2 * h + 1] = b;
                }
            }
        }
    }

    float* outp = spart + (size_t)bv * (BSZ * BSZ);
    const float SCL = 1.0f / 65535.0f;
#pragma unroll
    for (int w = 0; w < 4; ++w) {
        size_t jr = (size_t)(bj * TSJ + rl + 16 * w);
#pragma unroll
        for (int u = 0; u < 8; ++u) {
            int ic = bi * TSI + cl + 16 * u;
            outp[jr * BSZ + ic] = (float)acc[w][u] * SCL;
        }
    }
}

// ------- grid barrier: all-to-all flag barrier -------------------------------
__device__ inline void grid_barrier(unsigned* flags, unsigned gen) {
    __syncthreads();
    const int t = threadIdx.x;
    if (t == 0)
        __hip_atomic_store(&flags[blockIdx.x * 32], gen, __ATOMIC_RELEASE, __HIP_MEMORY_SCOPE_AGENT);
    if (t < NBLK) {
        while (__hip_atomic_load(&flags[t * 32], __ATOMIC_RELAXED, __HIP_MEMORY_SCOPE_AGENT) < gen)
            __builtin_amdgcn_s_sleep(1);
    }
    __syncthreads();
    if (t == 0)
        (void)__hip_atomic_load(&flags[0], __ATOMIC_ACQUIRE, __HIP_MEMORY_SCOPE_AGENT);
    __syncthreads();
}

// ---------------- Sinkhorn: R11 champion, verbatim ---------------------------
// Absorbs combine: staging reads 4 spart v-partials (sum -> W -> exp2 -> LDS);
// final sum re-reads spart. Regular launch; staggered atomic push.
__global__ __launch_bounds__(512) void sinkhorn_kernel(const float* __restrict__ spart,
                                                       float* __restrict__ cpart,
                                                       float* __restrict__ outpart,
                                                       float* __restrict__ out,
                                                       unsigned* __restrict__ flags) {
    __shared__ __align__(16) float k_lds[JPB * KPAD];   // 133,120 B
    __shared__ __align__(16) float a_sh[BSZ];
    __shared__ float b_sh[JPB];
    __shared__ float red[JPB];
    const int z = blockIdx.x;
    const int t = threadIdx.x;
    const int j0 = z * JPB;
    const int M = BSZ * BSZ;
    const float CE = -14.426950408889634f;  // -log2(e)/eps, eps=0.1
#pragma unroll
    for (int m = 0; m < 16; ++m) {
        int idx = t + 512 * m;
        int row = idx >> 8;
        int col = (idx & 255) * 4;
        size_t off = (size_t)(j0 + row) * BSZ + col;
        float4 w0 = *(const float4*)(spart + off);
        float4 w1 = *(const float4*)(spart + off + M);
        float4 w2 = *(const float4*)(spart + off + 2 * M);
        float4 w3 = *(const float4*)(spart + off + 3 * M);
        float4 k;
        k.x = exp2f(((w0.x + w1.x) + (w2.x + w3.x)) * CE);
        k.y = exp2f(((w0.y + w1.y) + (w2.y + w3.y)) * CE);
        k.z = exp2f(((w0.z + w1.z) + (w2.z + w3.z)) * CE);
        k.w = exp2f(((w0.w + w1.w) + (w2.w + w3.w)) * CE);
        *(float4*)(&k_lds[row * KPAD + col]) = k;
    }
    if (t < JPB) b_sh[t] = 1.0f;
    __syncthreads();
    const int jj = t >> 4;   // 0..31
    const int il = t & 15;
    const int colp = (t + z * 16) & 511;   // staggered column pair index
    unsigned gen = 1u;
    for (int it = 0; it < 20; ++it) {
        float* cbuf = cpart + (size_t)(it % 3) * BSZ;
        float2 s = {0.f, 0.f};
#pragma unroll
        for (int q = 0; q < JPB; ++q) {
            float2 kv = *(const float2*)(&k_lds[q * KPAD + 2 * colp]);
            float bb = b_sh[q];
            s.x += kv.x * bb; s.y += kv.y * bb;
        }
        (void)__hip_atomic_fetch_add(&cbuf[2 * colp],     s.x, __ATOMIC_RELAXED, __HIP_MEMORY_SCOPE_AGENT);
        (void)__hip_atomic_fetch_add(&cbuf[2 * colp + 1], s.y, __ATOMIC_RELAXED, __HIP_MEMORY_SCOPE_AGENT);
        grid_barrier(flags, gen++);
        float2 cv = *(const float2*)(&cbuf[2 * colp]);
        if (t < 32) cpart[(size_t)((it + 2) % 3) * BSZ + z * 32 + t] = 0.f;
        float2 ar;
        ar.x = 1.0f / cv.x; ar.y = 1.0f / cv.y;
        ((float2*)a_sh)[colp] = ar;
        __syncthreads();
        float sb = 0.f;
#pragma unroll
        for (int m2 = 0; m2 < 16; ++m2) {
            float4 kv = *(const float4*)(&k_lds[jj * KPAD + (il + 16 * m2) * 4]);
            float4 av = ((const float4*)a_sh)[il + 16 * m2];
            sb += (kv.x * av.x + kv.y * av.y) + (kv.z * av.z + kv.w * av.w);
        }
#pragma unroll
        for (int d = 8; d >= 1; d >>= 1) sb += __shfl_down(sb, d, 16);
        if (il == 0) b_sh[jj] = 1.0f / sb;
        __syncthreads();
    }
    {
        const float* wbase = spart + (size_t)(j0 + jj) * BSZ;
        float sb = 0.f;
#pragma unroll 4
        for (int m2 = 0; m2 < 16; ++m2) {
            int c4 = (il + 16 * m2) * 4;
            float4 kv = *(const float4*)(&k_lds[jj * KPAD + c4]);
            float4 av = ((const float4*)a_sh)[il + 16 * m2];
            float4 wa = *(const float4*)(wbase + c4);
            float4 wb = *(const float4*)(wbase + c4 + M);
            float4 wc = *(const float4*)(wbase + c4 + 2 * M);
            float4 wd = *(const float4*)(wbase + c4 + 3 * M);
            float4 wv;
            wv.x = (wa.x + wb.x) + (wc.x + wd.x);
            wv.y = (wa.y + wb.y) + (wc.y + wd.y);
            wv.z = (wa.z + wb.z) + (wc.z + wd.z);
            wv.w = (wa.w + wb.w) + (wc.w + wd.w);
            sb += (av.x * kv.x * wv.x + av.y * kv.y * wv.y) +
                  (av.z * kv.z * wv.z + av.w * kv.w * wv.w);
        }
#pragma unroll
        for (int d = 8; d >= 1; d >>= 1) sb += __shfl_down(sb, d, 16);
        if (il == 0) red[jj] = sb * b_sh[jj];
        __syncthreads();
        if (t == 0) {
            float ss = 0.f;
#pragma unroll
            for (int q = 0; q < JPB; ++q) ss += red[q];
            outpart[z] = ss;
        }
    }
    grid_barrier(flags, gen++);
    if (z == 0 && t == 0) {
        float ss = 0.f;
        for (int q = 0; q < NBLK; ++q) ss += outpart[q];
        out[0] = 0.001f * ss;
    }
}

extern "C" void kernel_launch(void* const* d_in, const int* in_sizes, int n_in,
                              void* d_out, int out_size, void* d_ws, size_t ws_size,
                              hipStream_t stream) {
    const float* ys = (const float*)d_in[0];
    const float* yt = (const float*)d_in[1];
    float* ws = (float*)d_ws;
    unsigned short* psh = (unsigned short*)ws;                        // 1024x4096 u16
    unsigned short* pth = (unsigned short*)(ws + 2ull * 1024 * 1024); // 1024x4096 u16
    float* spart   = ws + 4ull * 1024 * 1024;              // 4 x 1M floats
    float* wt      = spart + 4ull * BSZ * BSZ;             // 1M (unused)
    float* kt      = wt + (size_t)BSZ * BSZ;               // 1M (unused)
    float* cpart   = kt + (size_t)BSZ * BSZ;               // 3 x 1024 used
    float* outpart = cpart + 2ull * NBLK * BSZ;            // 32 (+pad)
    unsigned* flags = (unsigned*)(outpart + 128);          // NBLK x 32 uints
    float* outp    = (float*)d_out;

    softmax_kernel<<<dim3(2 * BSZ), dim3(256), 0, stream>>>(ys, yt, psh, pth, cpart, flags);
    cdist_kernel<<<dim3(8, 16, 4), dim3(256), 0, stream>>>(psh, pth, spart);
    sinkhorn_kernel<<<dim3(NBLK), dim3(512), 0, stream>>>(spart, cpart, outpart, outp, flags);
}